// Round 12
// baseline (40.618 us; speedup 1.0000x reference)
//
#include <hip/hip_runtime.h>
#include <hip/hip_bf16.h>

// LearnableInterpolation: out[b,t,n] = sum_o softmax_o(-3*(tpos[o,n]-tgt[t])^2) * x[b,o,n]
// B=32, L_org=L_to=2048, N=21. Softmax over o is a near-delta -> 17-tap window.
//
// R12: o-chunk decomposition. Evidence R9 (occupancy null) + R11 (store-
// coalescing null) isolates the 16.3us floor to the 2.75M stride-84B gather
// lane-requests (L1-miss stream). Fix: block = (b, 64-o-chunk); stage
// x[b, ob..ob+80, :21] as a CONTIGUOUS float4-coalesced 6.7KB tile (gather
// line-requests 2.75M -> 0.11M), then compute exactly the outputs whose
// 17-tap window STARTS in this chunk: per channel, the owning t-range is the
// analytic inverse of the monotone o0(t) (margin +-2), and the bit-exact
// claim-check (o0>>6)==kc partitions every (t,n) to exactly one block.
// k=0 / k=31 absorb the o0-clamp regions. Stores stay scattered (R11: free).
// Weight math identical to R9.

constexpr int LORG  = 2048;
constexpr int LTO   = 2048;
constexpr int NCH   = 21;
constexpr int BATCH = 32;
constexpr int W     = 8;
constexpr int NW    = 2 * W + 1;    // 17 taps
constexpr int C     = 64;           // o-chunk width
constexpr int KMAX  = LORG / C;     // 32 chunks
constexpr int RW    = C + 16;       // staged rows: chunk + window tail = 80
constexpr int NBLK  = BATCH * KMAX; // 1024 blocks

constexpr float MIN_RATIO = 0.7f, MAX_RATIO = 1.3f;
constexpr float MIN_BIAS  = -4.0f, MAX_BIAS = 4.0f;
constexpr float NEG3LOG2E = -3.0f * 1.4426950408889634f;  // log2-domain scale

__device__ __forceinline__ int compute_o0(float tg, float bb, float ir) {
    const float ocf = (float)LORG + (tg - bb) * ir;
    int o0 = (int)floorf(ocf + 0.5f) - W;
    return max(0, min(LORG - NW, o0));
}

__global__ __launch_bounds__(256) void li_chunk(
    const float* __restrict__ x,      // [B, LORG, NCH]
    const float* __restrict__ rmo,    // [NCH]
    const float* __restrict__ bias,   // [NCH]
    float* __restrict__ out)          // [B, LTO, NCH]
{
    // swizzle: 1024 = 8*128; consecutive wk = same b, adjacent chunks (the
    // 16-row chunk overlaps stay XCD-L2-local).
    const int h  = blockIdx.x;
    const int wk = (h & 7) * (NBLK / 8) + (h >> 3);
    const int b  = wk >> 5;                // 0..31
    const int kc = wk & 31;                // chunk index 0..31
    const int ob = kc * C;                 // chunk base in o
    const int rows = min(RW, LORG - ob);   // 80 (64 for kc=31)

    const int tid = threadIdx.x;

    __shared__ float xs[RW * NCH];         // 80*21 = 1680 floats (6.7 KB)
    __shared__ float rsh[NCH], bsh[NCH], irsh[NCH];
    __shared__ int   tlov[NCH], thiv[NCH];

    // ---- phase 0 (lanes 0..20): params + owning t-range per channel ----
    if (tid < NCH) {
        const float r  = fminf(fmaxf(rmo[tid] + 1.0f, MIN_RATIO), MAX_RATIO);
        const float bb = fminf(fmaxf(bias[tid], MIN_BIAS), MAX_BIAS);
        rsh[tid] = r;  bsh[tid] = bb;  irsh[tid] = 1.0f / r;
        // t-range with o0_unclamped(t) in [ob, ob+C):  f(t) >= o  <=>
        // t >= LTO + bb + r*(o + W - LORG - 0.5)
        const float tauL = (float)LTO + bb + r * ((float)(ob     + W - LORG) - 0.5f);
        const float tauH = (float)LTO + bb + r * ((float)(ob + C + W - LORG) - 0.5f);
        int Tlo = (kc == 0)        ? 0   : max(0,   (int)ceilf(tauL) - 2);
        int Thi = (kc == KMAX - 1) ? LTO : min(LTO, (int)ceilf(tauH) + 2);
        tlov[tid] = Tlo;
        thiv[tid] = Thi;
    }

    // ---- phase 1: stage contiguous x[b, ob..ob+rows, :21] as float4 ----
    const float4* src = (const float4*)(x + ((size_t)b * LORG + ob) * NCH);
    float4* xs4 = (float4*)xs;
    const int nf4 = rows * NCH / 4;        // 420 (or 336 for kc=31), exact
    for (int i = tid; i < nf4; i += 256) xs4[i] = src[i];
    __syncthreads();

    // ---- phase 2: per-wave channels, per-lane t candidates ----
    const int wv   = tid >> 6;
    const int lane = tid & 63;
    for (int n = wv; n < NCH; n += 4) {
        const float r  = rsh[n];
        const float bb = bsh[n];
        const float ir = irsh[n];
        const int Tlo = tlov[n], Thi = thiv[n];
        for (int t = Tlo + lane; t < Thi; t += 64) {
            const float tg = (float)(t - LTO);
            const int   o0 = compute_o0(tg, bb, ir);   // bit-exact everywhere
            if ((o0 >> 6) != kc) continue;             // claim-check (C=64)
            const int base = o0 - ob;                  // 0..63 (47 for kc=31)
            float d = (float)(o0 - LORG) * r + bb - tg;   // d_j = d + j*r
            // analytic max of -3*d_j^2 over j in [0,16]
            float js = floorf(-d * ir + 0.5f);
            js = fminf(fmaxf(js, 0.0f), 16.0f);
            const float ds = d + js * r;
            const float m  = NEG3LOG2E * ds * ds;      // log2-domain max
            float sum = 0.0f, acc = 0.0f;
            #pragma unroll
            for (int j = 0; j < NW; ++j) {
                const float wgt = exp2f(NEG3LOG2E * d * d - m);
                sum += wgt;
                acc = fmaf(wgt, xs[(base + j) * NCH + n], acc);
                d += r;
            }
            out[((size_t)b * LTO + t) * NCH + n] = acc * (1.0f / sum);
        }
    }
}

extern "C" void kernel_launch(void* const* d_in, const int* in_sizes, int n_in,
                              void* d_out, int out_size, void* d_ws, size_t ws_size,
                              hipStream_t stream) {
    const float* x    = (const float*)d_in[0];
    const float* rmo  = (const float*)d_in[1];
    const float* bias = (const float*)d_in[2];
    float* out = (float*)d_out;

    li_chunk<<<NBLK, 256, 0, stream>>>(x, rmo, bias, out);
}

// Round 13
// 38.152 us; speedup vs baseline: 1.0646x; 1.0646x over previous
//
#include <hip/hip_runtime.h>
#include <hip/hip_bf16.h>

// LearnableInterpolation: out[b,t,n] = sum_o softmax_o(-3*(tpos[o,n]-tgt[t])^2) * x[b,o,n]
// B=32, L_org=L_to=2048, N=21. Softmax over o is a near-delta -> 17-tap window.
//
// R13: o-chunk decomposition (R12: FETCH 21.7->2.7MB proven) with the lane
// waste fixed. R12 lost 2x to per-wave channel loops (t-ranges ~68 -> second
// 64-lane iteration nearly empty) and edge-chunk imbalance (Occupancy 11.7%).
// R13: C=32 chunks, 2048 blocks (8/CU, entire grid resident, 32 waves/CU);
// work items (n,t) FLATTENED per block: per-channel owning t-ranges ->
// prefix sum -> dense idx -> (n,t) via 5-step binary search over offs[].
// All lanes active except claim-check rejects (~10%) and the honest
// imbalance of edge chunks (bounded, correct for any input).
// Weight math VERBATIM from R12 — the analytic max-subtract is load-bearing:
// in o0-clamp regions |d|~200 => exp2 all-flush-to-0 => NaN without it.

constexpr int LORG  = 2048;
constexpr int LTO   = 2048;
constexpr int NCH   = 21;
constexpr int BATCH = 32;
constexpr int W     = 8;
constexpr int NW    = 2 * W + 1;    // 17 taps
constexpr int C     = 32;           // o-chunk width
constexpr int KMAX  = LORG / C;     // 64 chunks
constexpr int RW    = C + 16;       // staged rows: 48
constexpr int NBLK  = BATCH * KMAX; // 2048 blocks

constexpr float MIN_RATIO = 0.7f, MAX_RATIO = 1.3f;
constexpr float MIN_BIAS  = -4.0f, MAX_BIAS = 4.0f;
constexpr float NEG3LOG2E = -3.0f * 1.4426950408889634f;  // log2-domain scale

__device__ __forceinline__ int compute_o0(float tg, float bb, float ir) {
    const float ocf = (float)LORG + (tg - bb) * ir;
    int o0 = (int)floorf(ocf + 0.5f) - W;
    return max(0, min(LORG - NW, o0));
}

__global__ __launch_bounds__(256) void li_chunk(
    const float* __restrict__ x,      // [B, LORG, NCH]
    const float* __restrict__ rmo,    // [NCH]
    const float* __restrict__ bias,   // [NCH]
    float* __restrict__ out)          // [B, LTO, NCH]
{
    // swizzle: 2048 = 8*256; each XCD gets 4 b-slabs (all chunks), so the
    // 16-row chunk overlaps and x rows stay XCD-L2-local.
    const int h  = blockIdx.x;
    const int wk = (h & 7) * (NBLK / 8) + (h >> 3);
    const int b  = wk >> 6;                // 0..31
    const int kc = wk & 63;                // chunk index 0..63
    const int ob = kc * C;                 // chunk base in o
    const int rows = min(RW, LORG - ob);   // 48 (32 for kc=63)

    const int tid = threadIdx.x;

    __shared__ float xs[RW * NCH];         // 48*21 = 1008 floats (4 KB)
    __shared__ float rsh[NCH], bsh[NCH], irsh[NCH];
    __shared__ int   tlov[NCH], cntv[NCH];
    __shared__ int   offs[33];             // prefix offsets, padded with M

    // ---- stage: one float4 per thread (contiguous, coalesced) ----
    const float4* src = (const float4*)(x + ((size_t)b * LORG + ob) * NCH);
    float4* xs4 = (float4*)xs;
    const int nf4 = rows * NCH / 4;        // 252 (168 for kc=63)
    float4 v;
    if (tid < nf4) v = src[tid];

    // ---- params + owning t-range per channel (lanes 0..20) ----
    if (tid < NCH) {
        const float r  = fminf(fmaxf(rmo[tid] + 1.0f, MIN_RATIO), MAX_RATIO);
        const float bb = fminf(fmaxf(bias[tid], MIN_BIAS), MAX_BIAS);
        rsh[tid] = r;  bsh[tid] = bb;  irsh[tid] = 1.0f / r;
        // o0_unclamped(t) >= o  <=>  t >= LTO + bb + r*(o + W - LORG - 0.5)
        const float tauL = (float)LTO + bb + r * ((float)(ob     + W - LORG) - 0.5f);
        const float tauH = (float)LTO + bb + r * ((float)(ob + C + W - LORG) - 0.5f);
        const int Tlo = (kc == 0)        ? 0   : max(0,   (int)ceilf(tauL) - 2);
        const int Thi = (kc == KMAX - 1) ? LTO : min(LTO, (int)ceilf(tauH) + 2);
        tlov[tid] = Tlo;
        cntv[tid] = max(0, Thi - Tlo);     // clamp: range can be empty
    }
    if (tid < nf4) xs4[tid] = v;
    __syncthreads();

    // ---- prefix sum (trivial, once per block) ----
    if (tid == 0) {
        int a = 0;
        #pragma unroll
        for (int n = 0; n < NCH; ++n) { offs[n] = a; a += cntv[n]; }
        #pragma unroll
        for (int n = NCH; n < 33; ++n) offs[n] = a;   // pad with M
    }
    __syncthreads();

    const int M = offs[NCH];

    // ---- dense flat work loop: decode (n,t) by binary search ----
    for (int idx = tid; idx < M; idx += 256) {
        int n = 0;
        if (offs[n + 16] <= idx) n += 16;
        if (offs[n +  8] <= idx) n +=  8;
        if (offs[n +  4] <= idx) n +=  4;
        if (offs[n +  2] <= idx) n +=  2;
        if (offs[n +  1] <= idx) n +=  1;
        const int t = tlov[n] + (idx - offs[n]);

        const float r  = rsh[n];
        const float bb = bsh[n];
        const float ir = irsh[n];
        const float tg = (float)(t - LTO);
        const int   o0 = compute_o0(tg, bb, ir);   // bit-exact ownership
        if ((o0 >> 5) != kc) continue;             // claim-check (C=32)
        const int base = o0 - ob;                  // 0..31 (<=15 for kc=63)

        float d = (float)(o0 - LORG) * r + bb - tg;   // d_j = d + j*r
        // analytic max of -3*d_j^2 over j in [0,16] (LOAD-BEARING in clamp
        // regions where |d|~200: without it all exp2 flush to 0 -> NaN)
        float js = floorf(-d * ir + 0.5f);
        js = fminf(fmaxf(js, 0.0f), 16.0f);
        const float ds = d + js * r;
        const float m  = NEG3LOG2E * ds * ds;      // log2-domain max
        float sum = 0.0f, acc = 0.0f;
        #pragma unroll
        for (int j = 0; j < NW; ++j) {
            const float wgt = exp2f(NEG3LOG2E * d * d - m);
            sum += wgt;
            acc = fmaf(wgt, xs[(base + j) * NCH + n], acc);
            d += r;
        }
        out[((size_t)b * LTO + t) * NCH + n] = acc * (1.0f / sum);
    }
}

extern "C" void kernel_launch(void* const* d_in, const int* in_sizes, int n_in,
                              void* d_out, int out_size, void* d_ws, size_t ws_size,
                              hipStream_t stream) {
    const float* x    = (const float*)d_in[0];
    const float* rmo  = (const float*)d_in[1];
    const float* bias = (const float*)d_in[2];
    float* out = (float*)d_out;

    li_chunk<<<NBLK, 256, 0, stream>>>(x, rmo, bias, out);
}

// Round 14
// 17.272 us; speedup vs baseline: 2.3517x; 2.2089x over previous
//
#include <hip/hip_runtime.h>
#include <hip/hip_bf16.h>

// LearnableInterpolation: out[b,t,n] = sum_o softmax_o(-3*(tpos[o,n]-tgt[t])^2) * x[b,o,n]
// B=32, L_org=L_to=2048, N=21. Softmax over o is a near-delta.
//
// R14: fused-gather family (R9 16.3us), request-count attack:
//  - TT=128: loads/output drops 2.0 -> ~1.1-1.5 (window span amortized over
//    a bigger t-tile; 64-granularity ceiling was forcing 2.0 at TT=64).
//  - NW=9 (W=4): dropped softmax mass <= ~2e-13 relative (tap spacing
//    r>=0.7: nearest dropped tap |d|>=3.15 => e^-29.4) — zero accuracy risk
//    vs 1.5e-2 absmax headroom; halves exp2+FMA and shrinks windows.
//  - BH=8, wave owns 2 batches end-to-end: barrier-free per-wave LDS
//    (R6-proven), stage loop guarded by i<len (no clamp overfetch).
//  - weights: 2 sequential t-halves (17->9 regs per set), analytic
//    max-subtract kept (LOAD-BEARING in o0-clamp regions where |d|~200).
// Gather lane-requests 2.75M -> ~1.46M; scattered stores unchanged (proven
// free in L2 write-back; R7 taught us never to NT them).

constexpr int LORG  = 2048;
constexpr int LTO   = 2048;
constexpr int NCH   = 21;
constexpr int BATCH = 32;
constexpr int W     = 4;
constexpr int NW    = 2 * W + 1;    // 9 taps
constexpr int TT    = 128;          // t-tile
constexpr int BH    = 8;            // batches per block (2 per wave)
constexpr int XCAP  = 200;          // window cap: ceil(127/0.7)+1+9 = 192
constexpr int NBLK  = (LTO / TT) * NCH * (BATCH / BH);   // 16*21*4 = 1344

constexpr float MIN_RATIO = 0.7f, MAX_RATIO = 1.3f;
constexpr float MIN_BIAS  = -4.0f, MAX_BIAS = 4.0f;
constexpr float NEG3LOG2E = -3.0f * 1.4426950408889634f;  // log2-domain scale

__device__ __forceinline__ int compute_o0(float tg, float bb, float ir) {
    const float ocf = (float)LORG + (tg - bb) * ir;
    int o0 = (int)floorf(ocf + 0.5f) - W;
    return max(0, min(LORG - NW, o0));
}

__global__ __launch_bounds__(256) void li_fused(
    const float* __restrict__ x,      // [B, LORG, NCH]
    const float* __restrict__ rmo,    // [NCH]
    const float* __restrict__ bias,   // [NCH]
    float* __restrict__ out)          // [B, LTO, NCH]
{
    // XCD swizzle: 1344 = 8*168; bg fastest, then n, then t-tile, so blocks
    // sharing x rows (same t-tile) cluster on one XCD's L2.
    const int h    = blockIdx.x;
    const int wk   = (h & 7) * (NBLK / 8) + (h >> 3);
    const int bg   = wk & 3;               // batch group 0..3
    const int rest = wk >> 2;
    const int n    = rest % NCH;
    const int tt   = rest / NCH;           // 0..15
    const int t0   = tt * TT;
    const int b0   = bg * BH;

    const int tid  = threadIdx.x;
    const int lane = tid & 63;
    const int wv   = tid >> 6;             // wave id 0..3

    __shared__ float xs[BH][XCAP];         // 8*200*4B = 6.25 KB

    const float r  = fminf(fmaxf(rmo[n] + 1.0f, MIN_RATIO), MAX_RATIO);
    const float bb = fminf(fmaxf(bias[n], MIN_BIAS), MAX_BIAS);
    const float ir = 1.0f / r;

    // block-wide window (o0 monotone in t)
    const int lo  = compute_o0((float)(t0 - LTO), bb, ir);
    const int hi  = compute_o0((float)(t0 + TT - 1 - LTO), bb, ir);
    const int len = hi + NW - lo;          // <= 192 < XCAP

    // ---- per-wave staging of its 2 batches (barrier-free, guarded) ----
    const int mb = wv * 2;                 // local batches mb, mb+1
    {
        const float* colA = x + ((size_t)((b0 + mb    ) * LORG + lo)) * NCH + n;
        const float* colB = x + ((size_t)((b0 + mb + 1) * LORG + lo)) * NCH + n;
        for (int i = lane; i < len; i += 64) {
            xs[mb    ][i] = colA[(size_t)i * NCH];
            xs[mb + 1][i] = colB[(size_t)i * NCH];
        }
    }

    // ---- compute: 2 t-halves sequentially, 2 batches each ----
    #pragma unroll
    for (int half = 0; half < 2; ++half) {
        const int   tl = lane + 64 * half;
        const float tg = (float)(t0 + tl - LTO);
        const int   o0 = compute_o0(tg, bb, ir);
        const int base = o0 - lo;
        float d = (float)(o0 - LORG) * r + bb - tg;   // d_j = d + j*r
        // analytic max of -3*d_j^2 over j in [0,8]: nearest j to -d/r
        float js = floorf(-d * ir + 0.5f);
        js = fminf(fmaxf(js, 0.0f), 8.0f);
        const float ds = d + js * r;
        const float m  = NEG3LOG2E * ds * ds;         // log2-domain max
        float w[NW];
        float sum = 0.0f;
        #pragma unroll
        for (int j = 0; j < NW; ++j) {
            w[j] = exp2f(NEG3LOG2E * d * d - m);      // native v_exp_f32
            sum += w[j];
            d += r;
        }
        const float inv = 1.0f / sum;                 // sum >= 1, no NaN

        float accA = 0.0f, accB = 0.0f;
        #pragma unroll
        for (int j = 0; j < NW; ++j) {
            accA = fmaf(w[j], xs[mb    ][base + j], accA);
            accB = fmaf(w[j], xs[mb + 1][base + j], accB);
        }
        out[((size_t)(b0 + mb    ) * LTO + t0 + tl) * NCH + n] = accA * inv;
        out[((size_t)(b0 + mb + 1) * LTO + t0 + tl) * NCH + n] = accB * inv;
    }
}

extern "C" void kernel_launch(void* const* d_in, const int* in_sizes, int n_in,
                              void* d_out, int out_size, void* d_ws, size_t ws_size,
                              hipStream_t stream) {
    const float* x    = (const float*)d_in[0];
    const float* rmo  = (const float*)d_in[1];
    const float* bias = (const float*)d_in[2];
    float* out = (float*)d_out;

    li_fused<<<NBLK, 256, 0, stream>>>(x, rmo, bias, out);
}

// Round 15
// 16.224 us; speedup vs baseline: 2.5036x; 1.0646x over previous
//
#include <hip/hip_runtime.h>
#include <hip/hip_bf16.h>

// LearnableInterpolation: out[b,t,n] = sum_o softmax_o(-3*(tpos[o,n]-tgt[t])^2) * x[b,o,n]
// B=32, L_org=L_to=2048, N=21. Softmax over o is a near-delta.
//
// R15: deconfound R14. R14 cut scattered requests 17% (TT=128, NW=9) but
// ALSO dropped occupancy to 5.25 blocks/CU (1344 blocks) — the two canceled.
// R15 = R14's request count at R9's full occupancy: BH=4 (one batch per
// wave), 2688 blocks (10.5/CU, 32 waves/CU resident). Per wave: stage its
// batch's window (len<=192, guarded), compute 2 t-halves. Barrier-free
// per-wave LDS; weight math verbatim (analytic max-subtract load-bearing);
// NW=9 (dropped mass ~2e-13, absmax unchanged across R14). Regular stores.
// Pre-committed read: ~13.5-15us confirms request-rate model; ~16.3-17.5
// refutes it -> structural plateau, declare done next round.

constexpr int LORG  = 2048;
constexpr int LTO   = 2048;
constexpr int NCH   = 21;
constexpr int BATCH = 32;
constexpr int W     = 4;
constexpr int NW    = 2 * W + 1;    // 9 taps
constexpr int TT    = 128;          // t-tile
constexpr int BH    = 4;            // batches per block (1 per wave)
constexpr int XCAP  = 200;          // window cap: ceil(127/0.7)+1+9 = 192
constexpr int NBLK  = (LTO / TT) * NCH * (BATCH / BH);   // 16*21*8 = 2688

constexpr float MIN_RATIO = 0.7f, MAX_RATIO = 1.3f;
constexpr float MIN_BIAS  = -4.0f, MAX_BIAS = 4.0f;
constexpr float NEG3LOG2E = -3.0f * 1.4426950408889634f;  // log2-domain scale

__device__ __forceinline__ int compute_o0(float tg, float bb, float ir) {
    const float ocf = (float)LORG + (tg - bb) * ir;
    int o0 = (int)floorf(ocf + 0.5f) - W;
    return max(0, min(LORG - NW, o0));
}

__global__ __launch_bounds__(256) void li_fused(
    const float* __restrict__ x,      // [B, LORG, NCH]
    const float* __restrict__ rmo,    // [NCH]
    const float* __restrict__ bias,   // [NCH]
    float* __restrict__ out)          // [B, LTO, NCH]
{
    // XCD swizzle: 2688 = 8*336; bg fastest, then n, then t-tile, so blocks
    // sharing x rows (same t-tile) cluster on one XCD's L2.
    const int h    = blockIdx.x;
    const int wk   = (h & 7) * (NBLK / 8) + (h >> 3);
    const int bg   = wk & 7;               // batch group 0..7
    const int rest = wk >> 3;
    const int n    = rest % NCH;
    const int tt   = rest / NCH;           // 0..15
    const int t0   = tt * TT;
    const int b0   = bg * BH;

    const int tid  = threadIdx.x;
    const int lane = tid & 63;
    const int wv   = tid >> 6;             // wave id 0..3 -> its batch

    __shared__ float xs[BH][XCAP];         // 4*200*4B = 3.2 KB

    const float r  = fminf(fmaxf(rmo[n] + 1.0f, MIN_RATIO), MAX_RATIO);
    const float bb = fminf(fmaxf(bias[n], MIN_BIAS), MAX_BIAS);
    const float ir = 1.0f / r;

    // block-wide window (o0 monotone in t)
    const int lo  = compute_o0((float)(t0 - LTO), bb, ir);
    const int hi  = compute_o0((float)(t0 + TT - 1 - LTO), bb, ir);
    const int len = hi + NW - lo;          // <= 192 < XCAP

    // ---- per-wave staging of its batch (barrier-free, guarded) ----
    const int b = b0 + wv;
    {
        const float* col = x + ((size_t)(b * LORG + lo)) * NCH + n;
        for (int i = lane; i < len; i += 64)
            xs[wv][i] = col[(size_t)i * NCH];
    }

    // ---- compute: 2 t-halves sequentially, 1 batch ----
    #pragma unroll
    for (int half = 0; half < 2; ++half) {
        const int   tl = lane + 64 * half;
        const float tg = (float)(t0 + tl - LTO);
        const int   o0 = compute_o0(tg, bb, ir);
        const int base = o0 - lo;
        float d = (float)(o0 - LORG) * r + bb - tg;   // d_j = d + j*r
        // analytic max of -3*d_j^2 over j in [0,8]: nearest j to -d/r
        float js = floorf(-d * ir + 0.5f);
        js = fminf(fmaxf(js, 0.0f), 8.0f);
        const float ds = d + js * r;
        const float m  = NEG3LOG2E * ds * ds;         // log2-domain max
        float w[NW];
        float sum = 0.0f;
        #pragma unroll
        for (int j = 0; j < NW; ++j) {
            w[j] = exp2f(NEG3LOG2E * d * d - m);      // native v_exp_f32
            sum += w[j];
            d += r;
        }
        const float inv = 1.0f / sum;                 // sum >= 1, no NaN

        float acc = 0.0f;
        #pragma unroll
        for (int j = 0; j < NW; ++j)
            acc = fmaf(w[j], xs[wv][base + j], acc);
        out[((size_t)b * LTO + t0 + tl) * NCH + n] = acc * inv;
    }
}

extern "C" void kernel_launch(void* const* d_in, const int* in_sizes, int n_in,
                              void* d_out, int out_size, void* d_ws, size_t ws_size,
                              hipStream_t stream) {
    const float* x    = (const float*)d_in[0];
    const float* rmo  = (const float*)d_in[1];
    const float* bias = (const float*)d_in[2];
    float* out = (float*)d_out;

    li_fused<<<NBLK, 256, 0, stream>>>(x, rmo, bias, out);
}